// Round 3
// baseline (4657.842 us; speedup 1.0000x reference)
//
#include <hip/hip_runtime.h>
#include <cstdint>
#include <cstddef>

#define SEQ   512
#define BATCH 64
#define DIN   256
#define HDIM  1024
#define NGROUP 8      // batch groups
#define GROWS  8      // rows per group
#define NSLAB  32     // column slabs per group

typedef __attribute__((ext_vector_type(8)))  short  short8;
typedef __attribute__((ext_vector_type(4)))  float  float4v;

__device__ __forceinline__ short f2bf(float f) {
    union { float f; uint32_t u; } v; v.f = f;
    uint32_t u = v.u;
    uint32_t r = (u + 0x7fffu + ((u >> 16) & 1u)) >> 16;
    return (short)(r & 0xffffu);
}
__device__ __forceinline__ float bf2f(short s) {
    union { uint32_t u; float f; } v; v.u = ((uint32_t)(uint16_t)s) << 16;
    return v.f;
}
__device__ __forceinline__ float fast_tanh(float x) {
    float ax = __builtin_fabsf(x);
    float e  = __expf(-2.0f * ax);
    float r  = (1.0f - e) * __builtin_amdgcn_rcpf(1.0f + e);
    return __builtin_copysignf(r, x);
}

// ---------------------------------------------------------------------------
// prep: W_hh -> bf16 hi/lo planes; zero BOTH h buffers (tag bits must be 0)
// ---------------------------------------------------------------------------
__global__ void prep_kernel(const float* __restrict__ W_hh,
                            short* __restrict__ w_hi,
                            short* __restrict__ w_lo,
                            short* __restrict__ hbuf) {
    int tid = blockIdx.x * blockDim.x + threadIdx.x;
    int stride = gridDim.x * blockDim.x;
    for (int i = tid; i < HDIM * HDIM; i += stride) {
        float w = W_hh[i];
        short hi = f2bf(w);
        float lo = w - bf2f(hi);
        w_hi[i] = hi;
        w_lo[i] = f2bf(lo);
    }
    // zero both buffers, both planes: tag field 0 = "never written"
    for (int i = tid; i < 2 * 2 * BATCH * HDIM; i += stride) hbuf[i] = 0;
}

// ---------------------------------------------------------------------------
// xproj: out[r][j] = sum_i X[r][i] * Win[j][i] + bias[j]   (unchanged)
// ---------------------------------------------------------------------------
#define XBM 128
#define XBN 128
#define XBK 32

__global__ __launch_bounds__(256) void xproj_kernel(
    const float* __restrict__ X,
    const float* __restrict__ Win,
    const float* __restrict__ bias,
    float* __restrict__ out)
{
    __shared__ float As[XBK][XBM + 4];
    __shared__ float Bs[XBK][XBN + 4];
    const int bm = blockIdx.x;
    const int bn = blockIdx.y;
    const int r0 = bm * XBM, c0 = bn * XBN;
    const int tid = threadIdx.x;
    const int tx = tid & 15, ty = tid >> 4;

    float acc[8][8];
#pragma unroll
    for (int i = 0; i < 8; i++)
#pragma unroll
        for (int j = 0; j < 8; j++) acc[i][j] = 0.f;

    for (int k0 = 0; k0 < DIN; k0 += XBK) {
#pragma unroll
        for (int r = 0; r < 4; r++) {
            int row = (tid >> 3) + 32 * r;
            int kk  = (tid & 7) * 4;
            float4v v = *(const float4v*)(X + (size_t)(r0 + row) * DIN + k0 + kk);
            As[kk + 0][row] = v[0]; As[kk + 1][row] = v[1];
            As[kk + 2][row] = v[2]; As[kk + 3][row] = v[3];
        }
#pragma unroll
        for (int r = 0; r < 4; r++) {
            int row = (tid >> 3) + 32 * r;
            int kk  = (tid & 7) * 4;
            float4v v = *(const float4v*)(Win + (size_t)(c0 + row) * DIN + k0 + kk);
            Bs[kk + 0][row] = v[0]; Bs[kk + 1][row] = v[1];
            Bs[kk + 2][row] = v[2]; Bs[kk + 3][row] = v[3];
        }
        __syncthreads();
#pragma unroll
        for (int k = 0; k < XBK; k++) {
            float4v a0 = *(const float4v*)&As[k][ty * 8];
            float4v a1 = *(const float4v*)&As[k][ty * 8 + 4];
            float4v b0 = *(const float4v*)&Bs[k][tx * 8];
            float4v b1 = *(const float4v*)&Bs[k][tx * 8 + 4];
            float a[8] = {a0[0],a0[1],a0[2],a0[3],a1[0],a1[1],a1[2],a1[3]};
            float b[8] = {b0[0],b0[1],b0[2],b0[3],b1[0],b1[1],b1[2],b1[3]};
#pragma unroll
            for (int i = 0; i < 8; i++)
#pragma unroll
                for (int j = 0; j < 8; j++) acc[i][j] += a[i] * b[j];
        }
        __syncthreads();
    }

    float4v ba = *(const float4v*)(bias + c0 + tx * 8);
    float4v bb = *(const float4v*)(bias + c0 + tx * 8 + 4);
#pragma unroll
    for (int i = 0; i < 8; i++) {
        size_t row = (size_t)(r0 + ty * 8 + i);
        float4v v0, v1;
#pragma unroll
        for (int j = 0; j < 4; j++) { v0[j] = acc[i][j] + ba[j]; v1[j] = acc[i][4 + j] + bb[j]; }
        *(float4v*)(out + row * HDIM + c0 + tx * 8)     = v0;
        *(float4v*)(out + row * HDIM + c0 + tx * 8 + 4) = v1;
    }
}

// ---------------------------------------------------------------------------
// rnn4: 256 blocks x 512 threads. Block (g = blk&7, j = blk>>3): batch group g
// (8 rows), column slab j (32 cols). All h exchange via relaxed AGENT-scope
// u64 atomics (proven path, resolves at MALL). NO flags: each u64 h-packet
// carries a 2-bit step tag in the mantissa LSBs of its first bf16 element
// (hi-plane residual absorbed by lo plane -> numerically transparent).
// Consumers spin re-loading their own h packets until all tags match
// tau(t-1); producer needs no drain and no flag store. Tag period 6 steps,
// block skew <= 1 step (each block's overwrite is transitively gated by its
// own reads of all 32 slabs), zero-init tag = 0 (distinct).
// One __syncthreads per step (double-buffered zbuf); wave-0-only epilogue.
// ---------------------------------------------------------------------------
__global__ __launch_bounds__(512, 1) void rnn4_kernel(
    const float* __restrict__ alpha,
    const short* __restrict__ w_hi,
    const short* __restrict__ w_lo,
    short* __restrict__ hbuf,          // [2 buf][2 plane][BATCH][HDIM] bf16
    float* __restrict__ out)           // [SEQ][BATCH][HDIM] then h_n [BATCH][HDIM]
{
    __shared__ float zbuf[2][8][2][8][20];   // 40 KB; pad 20 -> conflict-free

    const int blk  = blockIdx.x;
    const int g    = blk & 7;           // batch group
    const int j    = blk >> 3;          // slab
    const int tid  = threadIdx.x;
    const int wave = tid >> 6;
    const int lane = tid & 63;

    const int kq   = wave;              // K-slice 0..7 (128 each)
    const int ln15 = lane & 15;
    const int kg   = lane >> 4;
    const int k_base = kq * 128 + kg * 8;

    // --- W fragments, register-resident: [nt][kt][plane] ---
    short8 wf[2][4][2];
#pragma unroll
    for (int nt = 0; nt < 2; nt++)
#pragma unroll
        for (int kt = 0; kt < 4; kt++) {
            int col = j * 32 + nt * 16 + ln15;
            int k   = k_base + kt * 32;
            wf[nt][kt][0] = *(const short8*)(w_hi + (size_t)col * HDIM + k);
            wf[nt][kt][1] = *(const short8*)(w_lo + (size_t)col * HDIM + k);
        }

    const int ar = g * GROWS + (ln15 & 7);  // A rows 8-15 duplicate 0-7 (C rows 8-15 unused)

    // --- wave-0 epilogue mapping: lane -> (row em, 4 cols c0..c0+3) ---
    const int em = lane >> 3;
    const int c0 = (lane & 7) * 4;
    const int erow = g * GROWS + em;
    const int egc  = j * 32 + c0;
    const int nt0 = c0 >> 4, n0 = c0 & 15;
    float hp[4] = {0.f, 0.f, 0.f, 0.f};
    float4v al4 = {0.f, 0.f, 0.f, 0.f};
    if (wave == 0) al4 = *(const float4v*)(alpha + egc);

    for (int t = 0; t < SEQ; t++) {
        const int cur = t & 1, nxt = cur ^ 1, par = cur;

        // xp load issued early (independent of the spin; own-lane address)
        float4v xpn = {0.f, 0.f, 0.f, 0.f};
        float* xaddr = out + (size_t)t * (BATCH * HDIM) + (size_t)erow * HDIM + egc;
        if (wave == 0) xpn = *(const float4v*)xaddr;

        // ---- load h packets, spinning until all 16 u64 tags match tau(t-1) ----
        const short* bh = hbuf + ((size_t)(cur * 2 + 0) * BATCH + ar) * HDIM + k_base;
        const short* bl = hbuf + ((size_t)(cur * 2 + 1) * BATCH + ar) * HDIM + k_base;
        const unsigned long long etag =
            (unsigned long long)((((unsigned)(t - 1) >> 1) % 3u) + 1u);
        union HU { unsigned long long u[2]; short8 s; } uh[4], ul[4];
        int ok, guard = 0;
        do {
            ok = 1;
#pragma unroll
            for (int kt = 0; kt < 4; kt++) {
                const unsigned long long* ph = (const unsigned long long*)(bh + kt * 32);
                const unsigned long long* pl = (const unsigned long long*)(bl + kt * 32);
                uh[kt].u[0] = __hip_atomic_load(ph,     __ATOMIC_RELAXED, __HIP_MEMORY_SCOPE_AGENT);
                uh[kt].u[1] = __hip_atomic_load(ph + 1, __ATOMIC_RELAXED, __HIP_MEMORY_SCOPE_AGENT);
                ul[kt].u[0] = __hip_atomic_load(pl,     __ATOMIC_RELAXED, __HIP_MEMORY_SCOPE_AGENT);
                ul[kt].u[1] = __hip_atomic_load(pl + 1, __ATOMIC_RELAXED, __HIP_MEMORY_SCOPE_AGENT);
            }
            if (t > 0) {
#pragma unroll
                for (int kt = 0; kt < 4; kt++) {
                    ok &= (int)((uh[kt].u[0] & 3ull) == etag) & (int)((uh[kt].u[1] & 3ull) == etag);
                    ok &= (int)((ul[kt].u[0] & 3ull) == etag) & (int)((ul[kt].u[1] & 3ull) == etag);
                }
            }
        } while (!ok && ++guard < (1 << 14));   // bounded: failure -> absmax, not hang

        // ---- MFMA over this wave's K-slice ----
        float4v acc0 = {0.f,0.f,0.f,0.f}, acc1 = {0.f,0.f,0.f,0.f};
#pragma unroll
        for (int kt = 0; kt < 4; kt++) {
            acc0 = __builtin_amdgcn_mfma_f32_16x16x32_bf16(uh[kt].s, wf[0][kt][0], acc0, 0, 0, 0);
            acc0 = __builtin_amdgcn_mfma_f32_16x16x32_bf16(uh[kt].s, wf[0][kt][1], acc0, 0, 0, 0);
            acc0 = __builtin_amdgcn_mfma_f32_16x16x32_bf16(ul[kt].s, wf[0][kt][0], acc0, 0, 0, 0);
            acc1 = __builtin_amdgcn_mfma_f32_16x16x32_bf16(uh[kt].s, wf[1][kt][0], acc1, 0, 0, 0);
            acc1 = __builtin_amdgcn_mfma_f32_16x16x32_bf16(uh[kt].s, wf[1][kt][1], acc1, 0, 0, 0);
            acc1 = __builtin_amdgcn_mfma_f32_16x16x32_bf16(ul[kt].s, wf[1][kt][0], acc1, 0, 0, 0);
        }
        // C/D layout: col = lane&15, row = (lane>>4)*4 + reg; only rows 0-7 valid
        if (kg < 2) {
#pragma unroll
            for (int reg = 0; reg < 4; reg++) {
                int m = kg * 4 + reg;
                zbuf[par][kq][0][m][ln15] = acc0[reg];
                zbuf[par][kq][1][m][ln15] = acc1[reg];
            }
        }
        __syncthreads();   // the ONLY barrier per step (zbuf double-buffered)

        // ---- epilogue: wave 0 only (64 lanes x 4 outputs) ----
        if (wave == 0) {
            float4v z = {0.f, 0.f, 0.f, 0.f};
#pragma unroll
            for (int q = 0; q < 8; q++) {
                float4v zz = *(const float4v*)&zbuf[par][q][nt0][em][n0];
                z += zz;
            }
#pragma unroll
            for (int i = 0; i < 4; i++) {
                float ht = fast_tanh(z[i] + xpn[i]);
                hp[i] = hp[i] + al4[i] * (ht - hp[i]);   // (1-a)h + a*ht
            }
            const unsigned wtag = (((unsigned)t >> 1) % 3u) + 1u;
            // hi plane: tag elem 0, residual absorbed by lo plane
            short h0 = f2bf(hp[0]);
            h0 = (short)(((unsigned short)h0 & ~3u) | wtag);
            short h1 = f2bf(hp[1]), h2 = f2bf(hp[2]), h3 = f2bf(hp[3]);
            short l0 = f2bf(hp[0] - bf2f(h0));
            short l1 = f2bf(hp[1] - bf2f(h1));
            short l2 = f2bf(hp[2] - bf2f(h2));
            short l3 = f2bf(hp[3] - bf2f(h3));
            l0 = (short)(((unsigned short)l0 & ~3u) | wtag);   // ~h*2^-16 noise
            unsigned long long packh =
                  (unsigned long long)(unsigned short)h0
                | ((unsigned long long)(unsigned short)h1 << 16)
                | ((unsigned long long)(unsigned short)h2 << 32)
                | ((unsigned long long)(unsigned short)h3 << 48);
            unsigned long long packl =
                  (unsigned long long)(unsigned short)l0
                | ((unsigned long long)(unsigned short)l1 << 16)
                | ((unsigned long long)(unsigned short)l2 << 32)
                | ((unsigned long long)(unsigned short)l3 << 48);
            unsigned long long* dhi =
                (unsigned long long*)(hbuf + ((size_t)(nxt * 2 + 0) * BATCH + erow) * HDIM + egc);
            unsigned long long* dlo =
                (unsigned long long*)(hbuf + ((size_t)(nxt * 2 + 1) * BATCH + erow) * HDIM + egc);
            __hip_atomic_store(dhi, packh, __ATOMIC_RELAXED, __HIP_MEMORY_SCOPE_AGENT);
            __hip_atomic_store(dlo, packl, __ATOMIC_RELAXED, __HIP_MEMORY_SCOPE_AGENT);
            // no drain, no flag: consumers self-validate via tags

            // deferred (off the critical path): out write, h_n write
            float4v resv = {hp[0], hp[1], hp[2], hp[3]};
            *(float4v*)xaddr = resv;
            if (t == SEQ - 1)
                *(float4v*)(out + (size_t)SEQ * BATCH * HDIM + (size_t)erow * HDIM + egc) = resv;
        }
    }
}

// ---------------------------------------------------------------------------
extern "C" void kernel_launch(void* const* d_in, const int* in_sizes, int n_in,
                              void* d_out, int out_size, void* d_ws, size_t ws_size,
                              hipStream_t stream) {
    const float* x     = (const float*)d_in[0];
    const float* W_in  = (const float*)d_in[1];
    const float* W_hh  = (const float*)d_in[2];
    const float* bias  = (const float*)d_in[3];
    const float* alpha = (const float*)d_in[4];
    float* out = (float*)d_out;

    short* w_hi = (short*)d_ws;                               // 2 MB
    short* w_lo = w_hi + (size_t)HDIM * HDIM;                 // 2 MB
    short* hbuf = w_lo + (size_t)HDIM * HDIM;                 // 512 KB

    prep_kernel<<<512, 256, 0, stream>>>(W_hh, w_hi, w_lo, hbuf);

    dim3 xg(SEQ * BATCH / XBM, HDIM / XBN);
    xproj_kernel<<<xg, 256, 0, stream>>>(x, W_in, bias, out);

    void* args[] = { (void*)&alpha, (void*)&w_hi, (void*)&w_lo,
                     (void*)&hbuf, (void*)&out };
    (void)hipLaunchCooperativeKernel((const void*)rnn4_kernel,
                                     dim3(NGROUP * NSLAB), dim3(512),
                                     args, 0, stream);
}

// Round 5
// 3027.240 us; speedup vs baseline: 1.5386x; 1.5386x over previous
//
#include <hip/hip_runtime.h>
#include <cstdint>
#include <cstddef>

#define SEQ   512
#define BATCH 64
#define DIN   256
#define HDIM  1024
#define NGROUP 8      // batch groups
#define GROWS  8      // rows per group
#define NSLAB  32     // column slabs per group
#define FLAGSTRIDE 32 // dwords between flags (128 B -> no cacheline sharing)

typedef __attribute__((ext_vector_type(8)))  short  short8;
typedef __attribute__((ext_vector_type(4)))  float  float4v;

__device__ __forceinline__ short f2bf(float f) {
    union { float f; uint32_t u; } v; v.f = f;
    uint32_t u = v.u;
    uint32_t r = (u + 0x7fffu + ((u >> 16) & 1u)) >> 16;
    return (short)(r & 0xffffu);
}
__device__ __forceinline__ float bf2f(short s) {
    union { uint32_t u; float f; } v; v.u = ((uint32_t)(uint16_t)s) << 16;
    return v.f;
}
__device__ __forceinline__ float fast_tanh(float x) {
    float ax = __builtin_fabsf(x);
    float e  = __expf(-2.0f * ax);
    float r  = (1.0f - e) * __builtin_amdgcn_rcpf(1.0f + e);
    return __builtin_copysignf(r, x);
}

// ---------------------------------------------------------------------------
// prep: W_hh -> bf16 hi/lo planes; zero both h buffers; zero prog flags
// ---------------------------------------------------------------------------
__global__ void prep_kernel(const float* __restrict__ W_hh,
                            short* __restrict__ w_hi,
                            short* __restrict__ w_lo,
                            short* __restrict__ hbuf,
                            unsigned int* __restrict__ prog) {
    int tid = blockIdx.x * blockDim.x + threadIdx.x;
    int stride = gridDim.x * blockDim.x;
    for (int i = tid; i < HDIM * HDIM; i += stride) {
        float w = W_hh[i];
        short hi = f2bf(w);
        float lo = w - bf2f(hi);
        w_hi[i] = hi;
        w_lo[i] = f2bf(lo);
    }
    for (int i = tid; i < 2 * 2 * BATCH * HDIM; i += stride) hbuf[i] = 0;
    for (int i = tid; i < NGROUP * NSLAB * FLAGSTRIDE; i += stride) prog[i] = 0u;
}

// ---------------------------------------------------------------------------
// xproj: out[r][j] = sum_i X[r][i] * Win[j][i] + bias[j]   (unchanged)
// ---------------------------------------------------------------------------
#define XBM 128
#define XBN 128
#define XBK 32

__global__ __launch_bounds__(256) void xproj_kernel(
    const float* __restrict__ X,
    const float* __restrict__ Win,
    const float* __restrict__ bias,
    float* __restrict__ out)
{
    __shared__ float As[XBK][XBM + 4];
    __shared__ float Bs[XBK][XBN + 4];
    const int bm = blockIdx.x;
    const int bn = blockIdx.y;
    const int r0 = bm * XBM, c0 = bn * XBN;
    const int tid = threadIdx.x;
    const int tx = tid & 15, ty = tid >> 4;

    float acc[8][8];
#pragma unroll
    for (int i = 0; i < 8; i++)
#pragma unroll
        for (int j = 0; j < 8; j++) acc[i][j] = 0.f;

    for (int k0 = 0; k0 < DIN; k0 += XBK) {
#pragma unroll
        for (int r = 0; r < 4; r++) {
            int row = (tid >> 3) + 32 * r;
            int kk  = (tid & 7) * 4;
            float4v v = *(const float4v*)(X + (size_t)(r0 + row) * DIN + k0 + kk);
            As[kk + 0][row] = v[0]; As[kk + 1][row] = v[1];
            As[kk + 2][row] = v[2]; As[kk + 3][row] = v[3];
        }
#pragma unroll
        for (int r = 0; r < 4; r++) {
            int row = (tid >> 3) + 32 * r;
            int kk  = (tid & 7) * 4;
            float4v v = *(const float4v*)(Win + (size_t)(c0 + row) * DIN + k0 + kk);
            Bs[kk + 0][row] = v[0]; Bs[kk + 1][row] = v[1];
            Bs[kk + 2][row] = v[2]; Bs[kk + 3][row] = v[3];
        }
        __syncthreads();
#pragma unroll
        for (int k = 0; k < XBK; k++) {
            float4v a0 = *(const float4v*)&As[k][ty * 8];
            float4v a1 = *(const float4v*)&As[k][ty * 8 + 4];
            float4v b0 = *(const float4v*)&Bs[k][tx * 8];
            float4v b1 = *(const float4v*)&Bs[k][tx * 8 + 4];
            float a[8] = {a0[0],a0[1],a0[2],a0[3],a1[0],a1[1],a1[2],a1[3]};
            float b[8] = {b0[0],b0[1],b0[2],b0[3],b1[0],b1[1],b1[2],b1[3]};
#pragma unroll
            for (int i = 0; i < 8; i++)
#pragma unroll
                for (int j = 0; j < 8; j++) acc[i][j] += a[i] * b[j];
        }
        __syncthreads();
    }

    float4v ba = *(const float4v*)(bias + c0 + tx * 8);
    float4v bb = *(const float4v*)(bias + c0 + tx * 8 + 4);
#pragma unroll
    for (int i = 0; i < 8; i++) {
        size_t row = (size_t)(r0 + ty * 8 + i);
        float4v v0, v1;
#pragma unroll
        for (int j = 0; j < 4; j++) { v0[j] = acc[i][j] + ba[j]; v1[j] = acc[i][4 + j] + bb[j]; }
        *(float4v*)(out + row * HDIM + c0 + tx * 8)     = v0;
        *(float4v*)(out + row * HDIM + c0 + tx * 8 + 4) = v1;
    }
}

// ---------------------------------------------------------------------------
// rnn5: 256 blocks x 512 threads. Block (g = blk&7, j = blk>>3).
// Exchange protocol = R0's PROVEN path: relaxed agent-scope u64 atomics for h,
// per-slab monotone flag, producer drains vmcnt(0) before flag store.
// Structure = R3's VERIFIED trims: per-wave poll of its 4 producer slabs only
// (union over 8 waves = all 32 slabs -> WAR-safe for the 2-buffer scheme,
// since epilogue stores sit after the barrier, after all waves' polls),
// single __syncthreads per step (double-buffered padded zbuf), wave-0-only
// epilogue, early xp load, fast_tanh, out/h_n stores AFTER the flag store
// (their HBM acks are off the critical drain).
// ---------------------------------------------------------------------------
__global__ __launch_bounds__(512, 1) void rnn5_kernel(
    const float* __restrict__ alpha,
    const short* __restrict__ w_hi,
    const short* __restrict__ w_lo,
    short* __restrict__ hbuf,          // [2 buf][2 plane][BATCH][HDIM] bf16
    unsigned int* __restrict__ prog,   // [NGROUP*NSLAB*FLAGSTRIDE]
    float* __restrict__ out)           // [SEQ][BATCH][HDIM] then h_n [BATCH][HDIM]
{
    __shared__ float zbuf[2][8][2][8][20];   // 40 KB; pad 20 -> conflict-free

    const int blk  = blockIdx.x;
    const int g    = blk & 7;           // batch group
    const int j    = blk >> 3;          // slab
    const int tid  = threadIdx.x;
    const int wave = tid >> 6;
    const int lane = tid & 63;

    const int kq   = wave;              // K-slice 0..7 (128 each)
    const int ln15 = lane & 15;
    const int kg   = lane >> 4;
    const int k_base = kq * 128 + kg * 8;

    // --- W fragments, register-resident: [nt][kt][plane] ---
    short8 wf[2][4][2];
#pragma unroll
    for (int nt = 0; nt < 2; nt++)
#pragma unroll
        for (int kt = 0; kt < 4; kt++) {
            int col = j * 32 + nt * 16 + ln15;
            int k   = k_base + kt * 32;
            wf[nt][kt][0] = *(const short8*)(w_hi + (size_t)col * HDIM + k);
            wf[nt][kt][1] = *(const short8*)(w_lo + (size_t)col * HDIM + k);
        }

    const int ar = g * GROWS + (ln15 & 7);  // A rows 8-15 duplicate 0-7 (C rows 8-15 unused)

    // --- wave-0 epilogue mapping: lane -> (row em, 4 cols c0..c0+3) ---
    const int em = lane >> 3;
    const int c0 = (lane & 7) * 4;
    const int erow = g * GROWS + em;
    const int egc  = j * 32 + c0;
    const int nt0 = c0 >> 4, n0 = c0 & 15;
    float hp[4] = {0.f, 0.f, 0.f, 0.f};
    float4v al4 = {0.f, 0.f, 0.f, 0.f};
    if (wave == 0) al4 = *(const float4v*)(alpha + egc);

    const unsigned int fi_own = (unsigned)(g * NSLAB + j) * FLAGSTRIDE;

    for (int t = 0; t < SEQ; t++) {
        const int cur = t & 1, nxt = cur ^ 1, par = cur;

        // xp load issued early (independent of the poll; overlaps it)
        float4v xpn = {0.f, 0.f, 0.f, 0.f};
        float* xaddr = out + (size_t)t * (BATCH * HDIM) + (size_t)erow * HDIM + egc;
        if (wave == 0) xpn = *(const float4v*)xaddr;

        // ---- per-wave poll: only this wave's 4 producer slabs ----
        if (t > 0) {
            if (lane < 4) {
                const unsigned int* pf =
                    prog + (unsigned)(g * NSLAB + kq * 4 + lane) * FLAGSTRIDE;
                int guard = 0;
                while (__hip_atomic_load(pf, __ATOMIC_RELAXED,
                                         __HIP_MEMORY_SCOPE_AGENT) < (unsigned)t
                       && ++guard < (1 << 16)) { }
            }
            asm volatile("" ::: "memory");   // no h load may hoist above the poll
        }

        // ---- load h packets ONCE (proven agent-scope atomic path) ----
        const short* bh = hbuf + ((size_t)(cur * 2 + 0) * BATCH + ar) * HDIM + k_base;
        const short* bl = hbuf + ((size_t)(cur * 2 + 1) * BATCH + ar) * HDIM + k_base;
        union HU { unsigned long long u[2]; short8 s; } uh[4], ul[4];
#pragma unroll
        for (int kt = 0; kt < 4; kt++) {
            const unsigned long long* ph = (const unsigned long long*)(bh + kt * 32);
            const unsigned long long* pl = (const unsigned long long*)(bl + kt * 32);
            uh[kt].u[0] = __hip_atomic_load(ph,     __ATOMIC_RELAXED, __HIP_MEMORY_SCOPE_AGENT);
            uh[kt].u[1] = __hip_atomic_load(ph + 1, __ATOMIC_RELAXED, __HIP_MEMORY_SCOPE_AGENT);
            ul[kt].u[0] = __hip_atomic_load(pl,     __ATOMIC_RELAXED, __HIP_MEMORY_SCOPE_AGENT);
            ul[kt].u[1] = __hip_atomic_load(pl + 1, __ATOMIC_RELAXED, __HIP_MEMORY_SCOPE_AGENT);
        }

        // ---- MFMA over this wave's K-slice ----
        float4v acc0 = {0.f,0.f,0.f,0.f}, acc1 = {0.f,0.f,0.f,0.f};
#pragma unroll
        for (int kt = 0; kt < 4; kt++) {
            acc0 = __builtin_amdgcn_mfma_f32_16x16x32_bf16(uh[kt].s, wf[0][kt][0], acc0, 0, 0, 0);
            acc0 = __builtin_amdgcn_mfma_f32_16x16x32_bf16(uh[kt].s, wf[0][kt][1], acc0, 0, 0, 0);
            acc0 = __builtin_amdgcn_mfma_f32_16x16x32_bf16(ul[kt].s, wf[0][kt][0], acc0, 0, 0, 0);
            acc1 = __builtin_amdgcn_mfma_f32_16x16x32_bf16(uh[kt].s, wf[1][kt][0], acc1, 0, 0, 0);
            acc1 = __builtin_amdgcn_mfma_f32_16x16x32_bf16(uh[kt].s, wf[1][kt][1], acc1, 0, 0, 0);
            acc1 = __builtin_amdgcn_mfma_f32_16x16x32_bf16(ul[kt].s, wf[1][kt][0], acc1, 0, 0, 0);
        }
        // C/D layout: col = lane&15, row = (lane>>4)*4 + reg; only rows 0-7 valid
        if (kg < 2) {
#pragma unroll
            for (int reg = 0; reg < 4; reg++) {
                int m = kg * 4 + reg;
                zbuf[par][kq][0][m][ln15] = acc0[reg];
                zbuf[par][kq][1][m][ln15] = acc1[reg];
            }
        }
        __syncthreads();   // the ONLY barrier per step (zbuf double-buffered)

        // ---- epilogue: wave 0 only (64 lanes x 4 outputs) ----
        if (wave == 0) {
            float4v z = {0.f, 0.f, 0.f, 0.f};
#pragma unroll
            for (int q = 0; q < 8; q++) {
                float4v zz = *(const float4v*)&zbuf[par][q][nt0][em][n0];
                z += zz;
            }
#pragma unroll
            for (int i = 0; i < 4; i++) {
                float ht = fast_tanh(z[i] + xpn[i]);
                hp[i] = hp[i] + al4[i] * (ht - hp[i]);   // (1-a)h + a*ht
            }
            short h0 = f2bf(hp[0]), h1 = f2bf(hp[1]), h2 = f2bf(hp[2]), h3 = f2bf(hp[3]);
            short l0 = f2bf(hp[0] - bf2f(h0)), l1 = f2bf(hp[1] - bf2f(h1));
            short l2 = f2bf(hp[2] - bf2f(h2)), l3 = f2bf(hp[3] - bf2f(h3));
            unsigned long long packh =
                  (unsigned long long)(unsigned short)h0
                | ((unsigned long long)(unsigned short)h1 << 16)
                | ((unsigned long long)(unsigned short)h2 << 32)
                | ((unsigned long long)(unsigned short)h3 << 48);
            unsigned long long packl =
                  (unsigned long long)(unsigned short)l0
                | ((unsigned long long)(unsigned short)l1 << 16)
                | ((unsigned long long)(unsigned short)l2 << 32)
                | ((unsigned long long)(unsigned short)l3 << 48);
            unsigned long long* dhi =
                (unsigned long long*)(hbuf + ((size_t)(nxt * 2 + 0) * BATCH + erow) * HDIM + egc);
            unsigned long long* dlo =
                (unsigned long long*)(hbuf + ((size_t)(nxt * 2 + 1) * BATCH + erow) * HDIM + egc);
            __hip_atomic_store(dhi, packh, __ATOMIC_RELAXED, __HIP_MEMORY_SCOPE_AGENT);
            __hip_atomic_store(dlo, packl, __ATOMIC_RELAXED, __HIP_MEMORY_SCOPE_AGENT);
            // drain ONLY the h stores (out/h_n writes are issued after the flag)
            asm volatile("s_waitcnt vmcnt(0)" ::: "memory");
            if (lane == 0)
                __hip_atomic_store(&prog[fi_own], (unsigned)(t + 1),
                                   __ATOMIC_RELAXED, __HIP_MEMORY_SCOPE_AGENT);
            asm volatile("" ::: "memory");
            // deferred (off the critical path): out write, h_n write
            float4v resv = {hp[0], hp[1], hp[2], hp[3]};
            *(float4v*)xaddr = resv;
            if (t == SEQ - 1)
                *(float4v*)(out + (size_t)SEQ * BATCH * HDIM + (size_t)erow * HDIM + egc) = resv;
        }
    }
}

// ---------------------------------------------------------------------------
extern "C" void kernel_launch(void* const* d_in, const int* in_sizes, int n_in,
                              void* d_out, int out_size, void* d_ws, size_t ws_size,
                              hipStream_t stream) {
    const float* x     = (const float*)d_in[0];
    const float* W_in  = (const float*)d_in[1];
    const float* W_hh  = (const float*)d_in[2];
    const float* bias  = (const float*)d_in[3];
    const float* alpha = (const float*)d_in[4];
    float* out = (float*)d_out;

    short* w_hi = (short*)d_ws;                               // 2 MB
    short* w_lo = w_hi + (size_t)HDIM * HDIM;                 // 2 MB
    short* hbuf = w_lo + (size_t)HDIM * HDIM;                 // 512 KB
    unsigned int* prog = (unsigned int*)(hbuf + (size_t)2 * 2 * BATCH * HDIM); // 32 KB

    prep_kernel<<<512, 256, 0, stream>>>(W_hh, w_hi, w_lo, hbuf, prog);

    dim3 xg(SEQ * BATCH / XBM, HDIM / XBN);
    xproj_kernel<<<xg, 256, 0, stream>>>(x, W_in, bias, out);

    void* args[] = { (void*)&alpha, (void*)&w_hi, (void*)&w_lo,
                     (void*)&hbuf, (void*)&prog, (void*)&out };
    (void)hipLaunchCooperativeKernel((const void*)rnn5_kernel,
                                     dim3(NGROUP * NSLAB), dim3(512),
                                     args, 0, stream);
}